// Round 9
// baseline (587.861 us; speedup 1.0000x reference)
//
#include <hip/hip_runtime.h>
#include <math.h>

typedef unsigned short ushortT;
typedef short bf8 __attribute__((ext_vector_type(8)));
typedef float f32x4 __attribute__((ext_vector_type(4)));
typedef unsigned short us4 __attribute__((ext_vector_type(4)));

__device__ __forceinline__ float bf2f(ushortT u){
    union { unsigned int i; float f; } v; v.i = ((unsigned int)u) << 16; return v.f;
}
__device__ __forceinline__ ushortT f2bf(float f){
    union { float f; unsigned int i; } v; v.f = f;
    unsigned int x = v.i;
    return (ushortT)((x + 0x7fffu + ((x >> 16) & 1u)) >> 16);
}
__device__ __forceinline__ float4 f4add(float4 a, float4 b){
    return make_float4(a.x + b.x, a.y + b.y, a.z + b.z, a.w + b.w);
}

// B=16, T=2000, D=300; fp32 I/O. DIM x DIM matvecs: bf16-split MFMA
// (xh*wh + xh*wl + xl*wh), M=32 tiles, A split into LDS fragments.
// Scan: 125 chunks x 16 steps per batch; enc reconstructed inside k_attn.

// ---------------- workspace layout (float indices), ~166.1 MB ----------------
constexpr size_t OFF_ART   = 0;           // 9,600,000  o (written by k_fused)
constexpr size_t OFF_R2    = 9600000;     // 9,600,000  S5 -> z
constexpr size_t OFF_GATE  = 19200000;    // 9,600,000  S2 -> gate
constexpr size_t OFF_HC    = 28800000;    // 8,544,000  coarse CE outputs
constexpr size_t OFF_WB    = 37344000;    //   972,800 f32 = 10 matrices bf16 hi/lo frags
constexpr size_t OFF_QEMB  = 38316800;    //   144,000
constexpr size_t OFF_KEYSQ = 38460800;    //   144,000
constexpr size_t OFF_OPTE  = 38604800;    //   307,200
constexpr size_t OFF_KEYS2 = 38912000;    //   307,200
constexpr size_t OFF_KEYS3 = 39219200;    //   307,200
constexpr size_t OFF_SCANA = 39526400;    //   600,000  (125 chunks x 4800)
constexpr size_t OFF_SCANB = 40126400;    //   600,000
constexpr size_t OFF_CST   = 40726400;    //   600,000  carry entering chunk c
constexpr size_t OFF_PART  = 41326400;    //   129,024
constexpr size_t OFF_MALL  = 41455424;    //    61,440  M_all = Q·K_all^T
// end = 41,516,864 floats = 166.1 MB (round-1 binary proved >=172.6 MB writable)

// HC rows: r2 [0,16000)=b*1000+g | r4 [16000,24000)=b*500+g
//          r10 [24000,27200)=b*200+g | r25 [27200,28480)=b*80+g
// S2 (at OFF_GATE): 16000 rows = b*1000+g | S5 (at OFF_R2): 6400 rows = b*400+g

// WB (ushort units): ((mp + kt)*19 + nt)*512 + lane*8 + j
//   mp = matrix*20 + part*10
//   matrix: 0..4 ce, 5 Wz, 6 Wo, 7 f1W, 8 f2W, 9 f3W; part: 0 hi, 1 lo

__global__ void k_pack(float* ws, const float* ceW, const float* Wz, const float* Wo,
                       const float* f1W, const float* f2W, const float* f3W){
    int id = blockIdx.x * 256 + threadIdx.x;
    if (id >= 972800) return;          // 10 * 97280
    int m = id / 97280; int rr = id % 97280;
    int kt = rr / 9728; rr %= 9728;
    int nt = rr / 512;  rr %= 512;
    int lane = rr / 8; int j = rr % 8;
    int d = kt * 32 + (lane >> 4) * 8 + j;
    int e = nt * 16 + (lane & 15);
    float w = 0.f;
    if (d < 300 && e < 300) {
        const float* src = (m < 5) ? (ceW + (size_t)m * 90000)
                         : (m == 5) ? Wz : (m == 6) ? Wo
                         : (m == 7) ? f1W : (m == 8) ? f2W : f3W;
        w = src[(size_t)e * 300 + d];
    }
    ushortT hi = f2bf(w);
    ushortT lo = f2bf(w - bf2f(hi));
    ushortT* wb = (ushortT*)(ws + OFF_WB);
    wb[((size_t)(m * 20 + kt) * 19 + nt) * 512 + lane * 8 + j] = hi;
    wb[((size_t)(m * 20 + 10 + kt) * 19 + nt) * 512 + lane * 8 + j] = lo;
}

__device__ __forceinline__ bf8 load_bfrag(const ushortT* wb, int mp, int kt, int nt, int lane){
    return *(const bf8*)(wb + (((size_t)(mp + kt) * 19 + nt) * 512 + lane * 8));
}
__device__ __forceinline__ bf8 lds_afrag(const ushortT* LA, int tile, int kt, int part, int lane){
    return *(const bf8*)(LA + ((tile * 10 + kt) * 2 + part) * 512 + lane * 8);
}
__device__ __forceinline__ void lds_store_split(ushortT* LA, int r, int dc4, float4 s){
    int kt = dc4 / 8;
    int kk = (dc4 % 8) * 4;
    int quad = kk / 8, j = kk % 8;
    int lane = quad * 16 + (r & 15), tile = r >> 4;
    us4 h, l;
    h.x = f2bf(s.x); l.x = f2bf(s.x - bf2f(h.x));
    h.y = f2bf(s.y); l.y = f2bf(s.y - bf2f(h.y));
    h.z = f2bf(s.z); l.z = f2bf(s.z - bf2f(h.z));
    h.w = f2bf(s.w); l.w = f2bf(s.w - bf2f(h.w));
    int base = ((tile * 10 + kt) * 2) * 512 + lane * 8 + j;
    *(us4*)&LA[base] = h;
    *(us4*)&LA[base + 512] = l;
}
__device__ __forceinline__ void lds_zero_kt9(ushortT* LA, int tid){
    for (int i = tid; i < 1024; i += 256) {
        int sl = i >> 8, u = i & 255;
        int slice = (sl < 2) ? (18 + sl) : (36 + sl); // 18,19,38,39
        *(unsigned int*)&LA[slice * 512 + u * 2] = 0u;
    }
}

// ---------------- gather: S2/S5 group sums (article) + q/opt embeddings ----------------
// blocks [0,160): article S2/S5, gb = b*10+c covers t in [c*200, c*200+200)
// blocks [160,513): question + options (flat f4 ids)
__global__ __launch_bounds__(320) void k_gather2(float* ws, const float* emb,
                         const int* art_in, const int* q_in,
                         const int* o1, const int* o2, const int* o3, const int* o4){
    int gb = blockIdx.x, tid = threadIdx.x;
    const float4* embv = (const float4*)emb;
    if (gb < 160) {
        if (tid >= 300) return;
        int b = gb / 10, c = gb % 10;
        int rg = tid / 75, d4 = tid % 75;
        int tbase = c * 200 + rg * 50;
        float4 s2 = make_float4(0.f,0.f,0.f,0.f), s5 = s2;
        float4* s2v = (float4*)(ws + OFF_GATE);
        float4* s5v = (float4*)(ws + OFF_R2);
        for (int i = 0; i < 50; i++) {
            int t = tbase + i;
            int tok = art_in[b * 2000 + t];
            float4 v = embv[(size_t)tok * 75 + d4];
            s2 = f4add(s2, v); s5 = f4add(s5, v);
            if ((i & 1) == 1) { s2v[((size_t)b * 1000 + (t >> 1)) * 75 + d4] = s2; s2 = make_float4(0.f,0.f,0.f,0.f); }
            if (i % 5 == 4)   { s5v[((size_t)b * 400 + t / 5) * 75 + d4] = s5;   s5 = make_float4(0.f,0.f,0.f,0.f); }
        }
    } else {
        int id = (gb - 160) * 320 + tid;
        if (id < 36000) {
            size_t row = id / 75; int wi = id % 75;
            ((float4*)(ws + OFF_QEMB))[id] = embv[(size_t)q_in[row] * 75 + wi];
        } else if (id < 112800) {
            int i3 = id - 36000; size_t row = i3 / 75; int wi = i3 % 75;
            int opt = (int)(row / 256); int rr = (int)(row % 256);
            const int* op = (opt == 0) ? o1 : (opt == 1) ? o2 : (opt == 2) ? o3 : o4;
            ((float4*)(ws + OFF_OPTE))[i3] = embv[(size_t)op[rr] * 75 + wi];
        }
    }
}

// ---------------- coarse CE (r=2,4,10,25): M=32, LDS-split A, MFMA ----------------
// blocks: [0,40) r25 | [40,140) r10 | [140,390) r4 | [390,890) r2
__global__ __launch_bounds__(256) void k_ce_coarse(float* ws, const float* ceb){
    int gb = blockIdx.x;
    int kind, rows0, wi, rowLocal0;
    if (gb < 40)       { kind = 3; rows0 = 27200; wi = 4; rowLocal0 = gb * 32; }
    else if (gb < 140) { kind = 2; rows0 = 24000; wi = 3; rowLocal0 = (gb - 40) * 32; }
    else if (gb < 390) { kind = 1; rows0 = 16000; wi = 2; rowLocal0 = (gb - 140) * 32; }
    else               { kind = 0; rows0 = 0;     wi = 1; rowLocal0 = (gb - 390) * 32; }

    __shared__ ushortT LA[20480];
    int tid = threadIdx.x;
    lds_zero_kt9(LA, tid);
    __syncthreads();
    const float4* S2v = (const float4*)(ws + OFF_GATE);
    const float4* S5v = (const float4*)(ws + OFF_R2);
    for (int v = tid; v < 2400; v += 256) {
        int r = v / 75, dc4 = v % 75;
        int R = rowLocal0 + r;
        float4 s;
        if (kind == 0) {
            s = S2v[(size_t)R * 75 + dc4];
        } else if (kind == 1) {
            int b = R / 500, g = R % 500;
            const float4* p = S2v + ((size_t)b * 1000 + 2 * g) * 75 + dc4;
            s = f4add(p[0], p[75]);
        } else if (kind == 2) {
            int b = R / 200, g = R % 200;
            const float4* p = S5v + ((size_t)b * 400 + 2 * g) * 75 + dc4;
            s = f4add(p[0], p[75]);
        } else {
            int b = R / 80, g = R % 80;
            const float4* p = S5v + ((size_t)b * 400 + 5 * g) * 75 + dc4;
            s = f4add(f4add(p[0], p[75]), f4add(p[150], p[225]));
            s = f4add(s, p[300]);
        }
        lds_store_split(LA, r, dc4, s);
    }
    __syncthreads();

    int lane = tid & 63, wv = tid >> 6;
    int mrow = lane & 15, quad = lane >> 4;
    const ushortT* wb = (const ushortT*)(ws + OFF_WB);
    int mpH = wi * 20, mpL = wi * 20 + 10;

    for (int p = 0; p < 5; p++) {
        int nt = wv + p * 4; if (nt >= 19) break;
        f32x4 a0 = {0.f,0.f,0.f,0.f}, a1 = {0.f,0.f,0.f,0.f};
        #pragma unroll
        for (int kt = 0; kt < 10; kt++) {
            bf8 Ah0 = lds_afrag(LA, 0, kt, 0, lane), Al0 = lds_afrag(LA, 0, kt, 1, lane);
            bf8 Ah1 = lds_afrag(LA, 1, kt, 0, lane), Al1 = lds_afrag(LA, 1, kt, 1, lane);
            bf8 Bh = load_bfrag(wb, mpH, kt, nt, lane);
            bf8 Bl = load_bfrag(wb, mpL, kt, nt, lane);
            a0 = __builtin_amdgcn_mfma_f32_16x16x32_bf16(Ah0, Bh, a0, 0, 0, 0);
            a1 = __builtin_amdgcn_mfma_f32_16x16x32_bf16(Ah1, Bh, a1, 0, 0, 0);
            a0 = __builtin_amdgcn_mfma_f32_16x16x32_bf16(Ah0, Bl, a0, 0, 0, 0);
            a1 = __builtin_amdgcn_mfma_f32_16x16x32_bf16(Ah1, Bl, a1, 0, 0, 0);
            a0 = __builtin_amdgcn_mfma_f32_16x16x32_bf16(Al0, Bh, a0, 0, 0, 0);
            a1 = __builtin_amdgcn_mfma_f32_16x16x32_bf16(Al1, Bh, a1, 0, 0, 0);
        }
        int e = nt * 16 + mrow;
        if (e < 300) {
            float bv = ceb[wi * 300 + e];
            #pragma unroll
            for (int q = 0; q < 4; q++) {
                int r0 = rows0 + rowLocal0 + quad * 4 + q;
                ws[OFF_HC + (size_t)r0 * 300 + e] = fmaxf(a0[q] + bv, 0.f);
                ws[OFF_HC + (size_t)(r0 + 16) * 300 + e] = fmaxf(a1[q] + bv, 0.f);
            }
        }
    }
}

// ---------------- fused: ce0 + Wz + Wo MFMA (A gathered from emb) + epilogue ----------------
// gate -> GATE, z -> R2, o -> ART
__global__ __launch_bounds__(256) void k_fused(float* ws, const float* emb, const int* art_in,
                                               const float* ceb,
                                               const float* m1W, const float* m1b,
                                               const float* m2W, const float* m2b,
                                               const float* bz, const float* bo){
    int row0 = blockIdx.x * 32;
    __shared__ ushortT LA[20480];
    int tid = threadIdx.x;
    lds_zero_kt9(LA, tid);
    __syncthreads();
    const float4* embv = (const float4*)emb;
    for (int v = tid; v < 2400; v += 256) {
        int r = v / 75, dc4 = v % 75;
        int tok = art_in[row0 + r];
        float4 s = embv[(size_t)tok * 75 + dc4];
        lds_store_split(LA, r, dc4, s);
    }
    __syncthreads();

    float w1[3][5], b1[3], w2[3], b2;
    #pragma unroll
    for (int k = 0; k < 3; k++) {
        #pragma unroll
        for (int i = 0; i < 5; i++) w1[k][i] = m1W[k * 5 + i];
        b1[k] = m1b[k]; w2[k] = m2W[k];
    }
    b2 = m2b[0];

    int lane = tid & 63, wv = tid >> 6;
    int mrow = lane & 15, quad = lane >> 4;
    const ushortT* wb = (const ushortT*)(ws + OFF_WB);

    for (int p = 0; p < 5; p++) {
        int nt = wv + p * 4; if (nt >= 19) break;
        f32x4 aA0 = {0.f,0.f,0.f,0.f}, aA1 = aA0;
        f32x4 aZ0 = aA0, aZ1 = aA0, aO0 = aA0, aO1 = aA0;
        #pragma unroll
        for (int kt = 0; kt < 10; kt++) {
            bf8 Ah0 = lds_afrag(LA, 0, kt, 0, lane), Al0 = lds_afrag(LA, 0, kt, 1, lane);
            bf8 Ah1 = lds_afrag(LA, 1, kt, 0, lane), Al1 = lds_afrag(LA, 1, kt, 1, lane);
            bf8 BAh = load_bfrag(wb, 0,   kt, nt, lane);
            bf8 BAl = load_bfrag(wb, 10,  kt, nt, lane);
            bf8 BZh = load_bfrag(wb, 100, kt, nt, lane);
            bf8 BZl = load_bfrag(wb, 110, kt, nt, lane);
            bf8 BOh = load_bfrag(wb, 120, kt, nt, lane);
            bf8 BOl = load_bfrag(wb, 130, kt, nt, lane);
            aA0 = __builtin_amdgcn_mfma_f32_16x16x32_bf16(Ah0, BAh, aA0, 0, 0, 0);
            aZ0 = __builtin_amdgcn_mfma_f32_16x16x32_bf16(Ah0, BZh, aZ0, 0, 0, 0);
            aO0 = __builtin_amdgcn_mfma_f32_16x16x32_bf16(Ah0, BOh, aO0, 0, 0, 0);
            aA1 = __builtin_amdgcn_mfma_f32_16x16x32_bf16(Ah1, BAh, aA1, 0, 0, 0);
            aZ1 = __builtin_amdgcn_mfma_f32_16x16x32_bf16(Ah1, BZh, aZ1, 0, 0, 0);
            aO1 = __builtin_amdgcn_mfma_f32_16x16x32_bf16(Ah1, BOh, aO1, 0, 0, 0);
            aA0 = __builtin_amdgcn_mfma_f32_16x16x32_bf16(Ah0, BAl, aA0, 0, 0, 0);
            aZ0 = __builtin_amdgcn_mfma_f32_16x16x32_bf16(Ah0, BZl, aZ0, 0, 0, 0);
            aO0 = __builtin_amdgcn_mfma_f32_16x16x32_bf16(Ah0, BOl, aO0, 0, 0, 0);
            aA1 = __builtin_amdgcn_mfma_f32_16x16x32_bf16(Ah1, BAl, aA1, 0, 0, 0);
            aZ1 = __builtin_amdgcn_mfma_f32_16x16x32_bf16(Ah1, BZl, aZ1, 0, 0, 0);
            aO1 = __builtin_amdgcn_mfma_f32_16x16x32_bf16(Ah1, BOl, aO1, 0, 0, 0);
            aA0 = __builtin_amdgcn_mfma_f32_16x16x32_bf16(Al0, BAh, aA0, 0, 0, 0);
            aZ0 = __builtin_amdgcn_mfma_f32_16x16x32_bf16(Al0, BZh, aZ0, 0, 0, 0);
            aO0 = __builtin_amdgcn_mfma_f32_16x16x32_bf16(Al0, BOh, aO0, 0, 0, 0);
            aA1 = __builtin_amdgcn_mfma_f32_16x16x32_bf16(Al1, BAh, aA1, 0, 0, 0);
            aZ1 = __builtin_amdgcn_mfma_f32_16x16x32_bf16(Al1, BZh, aZ1, 0, 0, 0);
            aO1 = __builtin_amdgcn_mfma_f32_16x16x32_bf16(Al1, BOh, aO1, 0, 0, 0);
        }
        int e = nt * 16 + mrow;
        if (e < 300) {
            float cebe = ceb[e], bze = bz[e], boe = bo[e];
            #pragma unroll
            for (int tile = 0; tile < 2; tile++) {
                #pragma unroll
                for (int q = 0; q < 4; q++) {
                    float vA = tile ? aA1[q] : aA0[q];
                    float vZ = tile ? aZ1[q] : aZ0[q];
                    float vO = tile ? aO1[q] : aO0[q];
                    int row = row0 + tile * 16 + quad * 4 + q;
                    int bb = row / 2000, t = row % 2000;
                    size_t c1 = OFF_HC + ((size_t)bb * 1000 + t / 2) * 300;
                    size_t c2 = OFF_HC + (16000 + (size_t)bb * 500 + t / 4) * 300;
                    size_t c3 = OFF_HC + (24000 + (size_t)bb * 200 + t / 10) * 300;
                    size_t c4 = OFF_HC + (27200 + (size_t)bb * 80 + t / 25) * 300;
                    float y0 = fmaxf(vA + cebe, 0.f);
                    float y1 = ws[c1 + e] * 0.5f;
                    float y2 = ws[c2 + e] * 0.25f;
                    float y3 = ws[c3 + e] * 0.1f;
                    float y4 = ws[c4 + e] * 0.04f;
                    float gacc = b2;
                    #pragma unroll
                    for (int k = 0; k < 3; k++) {
                        float a = b1[k] + y0 * w1[k][0] + y1 * w1[k][1] + y2 * w1[k][2]
                                + y3 * w1[k][3] + y4 * w1[k][4];
                        gacc += fmaxf(a, 0.f) * w2[k];
                    }
                    ws[OFF_GATE + (size_t)row * 300 + e] = fmaxf(gacc, 0.f);
                    ws[OFF_R2 + (size_t)row * 300 + e] = tanhf(vZ + bze);
                    ws[OFF_ART + (size_t)row * 300 + e] = tanhf(vO + boe);
                }
            }
        }
    }
}

// ---------------- MRU scan: 125 chunks x 16 steps per batch ----------------
__global__ void k_scan1(float* ws){
    int tid = blockIdx.x * 256 + threadIdx.x;
    if (tid >= 600000) return;
    int c = tid / 4800, ch = tid % 4800;
    int b = ch / 300, d = ch % 300;
    size_t base = (size_t)b * 2000 * 300 + d;
    float A = 1.f, Bv = 0.f;
    int t0 = c * 16;
    for (int k = 0; k < 16; k++) {
        size_t ix = base + (size_t)(t0 + k) * 300;
        float g = ws[OFF_GATE + ix], zz = ws[OFF_R2 + ix];
        Bv = g * Bv + (1.f - g) * zz;
        A *= g;
    }
    ws[OFF_SCANA + tid] = A;
    ws[OFF_SCANB + tid] = Bv;
}

__global__ void k_scan2(float* ws){
    int ch = blockIdx.x * 256 + threadIdx.x;
    if (ch >= 4800) return;
    float c = 0.f;
    for (int j = 0; j < 125; j++) {
        ws[OFF_CST + (size_t)j * 4800 + ch] = c;
        c = ws[OFF_SCANA + (size_t)j * 4800 + ch] * c + ws[OFF_SCANB + (size_t)j * 4800 + ch];
    }
}

// ---------------- key projections via MFMA: f1(q), f2(opt), f3(opt) ----------------
__global__ __launch_bounds__(256) void k_keysm(float* ws, const float* f1b,
                                               const float* f2b, const float* f3b){
    int gb = blockIdx.x;
    int wm, rowLocal0; size_t inoff, outoff; const float* bias;
    if (gb < 15)      { wm = 7; inoff = OFF_QEMB; outoff = OFF_KEYSQ; bias = f1b; rowLocal0 = gb * 32; }
    else if (gb < 47) { wm = 8; inoff = OFF_OPTE; outoff = OFF_KEYS2; bias = f2b; rowLocal0 = (gb - 15) * 32; }
    else              { wm = 9; inoff = OFF_OPTE; outoff = OFF_KEYS3; bias = f3b; rowLocal0 = (gb - 47) * 32; }

    __shared__ ushortT LA[20480];
    int tid = threadIdx.x;
    lds_zero_kt9(LA, tid);
    __syncthreads();
    for (int v = tid; v < 2400; v += 256) {
        int r = v / 75, dc4 = v % 75;
        float4 s = *(const float4*)&ws[inoff + (size_t)(rowLocal0 + r) * 300 + dc4 * 4];
        lds_store_split(LA, r, dc4, s);
    }
    __syncthreads();

    int lane = tid & 63, wv = tid >> 6;
    int mrow = lane & 15, quad = lane >> 4;
    const ushortT* wb = (const ushortT*)(ws + OFF_WB);
    int mpH = wm * 20, mpL = wm * 20 + 10;

    for (int p = 0; p < 5; p++) {
        int nt = wv + p * 4; if (nt >= 19) break;
        f32x4 a0 = {0.f,0.f,0.f,0.f}, a1 = {0.f,0.f,0.f,0.f};
        #pragma unroll
        for (int kt = 0; kt < 10; kt++) {
            bf8 Ah0 = lds_afrag(LA, 0, kt, 0, lane), Al0 = lds_afrag(LA, 0, kt, 1, lane);
            bf8 Ah1 = lds_afrag(LA, 1, kt, 0, lane), Al1 = lds_afrag(LA, 1, kt, 1, lane);
            bf8 Bh = load_bfrag(wb, mpH, kt, nt, lane);
            bf8 Bl = load_bfrag(wb, mpL, kt, nt, lane);
            a0 = __builtin_amdgcn_mfma_f32_16x16x32_bf16(Ah0, Bh, a0, 0, 0, 0);
            a1 = __builtin_amdgcn_mfma_f32_16x16x32_bf16(Ah1, Bh, a1, 0, 0, 0);
            a0 = __builtin_amdgcn_mfma_f32_16x16x32_bf16(Ah0, Bl, a0, 0, 0, 0);
            a1 = __builtin_amdgcn_mfma_f32_16x16x32_bf16(Ah1, Bl, a1, 0, 0, 0);
            a0 = __builtin_amdgcn_mfma_f32_16x16x32_bf16(Al0, Bh, a0, 0, 0, 0);
            a1 = __builtin_amdgcn_mfma_f32_16x16x32_bf16(Al1, Bh, a1, 0, 0, 0);
        }
        int e = nt * 16 + mrow;
        if (e < 300) {
            float bv = bias[e];
            #pragma unroll
            for (int q = 0; q < 4; q++) {
                int r0 = rowLocal0 + quad * 4 + q;
                ws[outoff + (size_t)r0 * 300 + e] = a0[q] + bv;
                ws[outoff + (size_t)(r0 + 16) * 300 + e] = a1[q] + bv;
            }
        }
    }
}

// ---------------- M_all = Q · K_all^T per batch (30 x 128, K=300) ----------------
__global__ __launch_bounds__(256) void k_matt(float* ws){
    int b = blockIdx.x;
    __shared__ float Q[30 * 300];
    int tid = threadIdx.x;
    for (int v = tid; v < 2250; v += 256)
        *(float4*)&Q[v * 4] = *(const float4*)&ws[OFF_QEMB + (size_t)b * 9000 + (size_t)v * 4];
    __syncthreads();
    int cw = tid & 127, half = tid >> 7;
    int combo = cw >> 4, w = cw & 15;
    size_t kbase = (combo < 4)
        ? OFF_KEYS2 + ((size_t)combo * 256 + (size_t)b * 16 + w) * 300
        : OFF_KEYS3 + ((size_t)(combo - 4) * 256 + (size_t)b * 16 + w) * 300;
    const float4* kr = (const float4*)&ws[kbase];
    for (int wp = half * 15; wp < half * 15 + 15; wp++) {
        const float4* qr = (const float4*)&Q[wp * 300];
        float a = 0.f;
        #pragma unroll 5
        for (int j = 0; j < 75; j++) {
            float4 k = kr[j], q = qr[j];
            a += k.x * q.x + k.y * q.y + k.z * q.z + k.w * q.w;
        }
        ws[OFF_MALL + (size_t)b * 3840 + (size_t)wp * 128 + cw] = a;
    }
}

// ---------------- attention: enc reconstructed from g/z/o + CST, then factored scores ----------------
__global__ __launch_bounds__(256) void k_attn(float* ws){
    int tile = blockIdx.x, b = blockIdx.y;
    int t0 = tile * 32;
    __shared__ __align__(16) float U[9728];
    __shared__ float S[32 * 30];
    int tid = threadIdx.x;

    // phase 1a: reconstruct enc tile (stride 304) via 32-step cs replay per d
    for (int d = tid; d < 304; d += 256) {
        if (d < 300) {
            float cc = ws[OFF_CST + (size_t)(2 * tile) * 4800 + (size_t)b * 300 + d];
            size_t base = (size_t)b * 2000 * 300 + d;
            for (int i = 0; i < 32; i++) {
                int t = t0 + i;
                float ev = 0.f;
                if (t < 2000) {
                    size_t ix = base + (size_t)t * 300;
                    float g = ws[OFF_GATE + ix], zz = ws[OFF_R2 + ix], oo = ws[OFF_ART + ix];
                    cc = g * cc + (1.f - g) * zz;
                    ev = oo * cc;
                }
                U[i * 304 + d] = ev;
            }
        } else {
            for (int i = 0; i < 32; i++) U[i * 304 + d] = 0.f;
        }
    }
    __syncthreads();

    // phase 1b: S1 = enc_tile · K1^T (32x30)
    if (tid < 240) {
        int q = tid / 30, w = tid % 30;
        const float4* kr = (const float4*)&ws[OFF_KEYSQ + (size_t)b * 9000 + (size_t)w * 300];
        const float4* x0 = (const float4*)&U[(q * 4 + 0) * 304];
        const float4* x1 = (const float4*)&U[(q * 4 + 1) * 304];
        const float4* x2 = (const float4*)&U[(q * 4 + 2) * 304];
        const float4* x3 = (const float4*)&U[(q * 4 + 3) * 304];
        float a0 = 0.f, a1 = 0.f, a2 = 0.f, a3 = 0.f;
        #pragma unroll 5
        for (int j = 0; j < 75; j++) {
            float4 k = kr[j];
            float4 v0 = x0[j], v1 = x1[j], v2 = x2[j], v3 = x3[j];
            a0 += v0.x * k.x + v0.y * k.y + v0.z * k.z + v0.w * k.w;
            a1 += v1.x * k.x + v1.y * k.y + v1.z * k.z + v1.w * k.w;
            a2 += v2.x * k.x + v2.y * k.y + v2.z * k.z + v2.w * k.w;
            a3 += v3.x * k.x + v3.y * k.y + v3.z * k.z + v3.w * k.w;
        }
        S[(q * 4 + 0) * 30 + w] = a0;
        S[(q * 4 + 1) * 30 + w] = a1;
        S[(q * 4 + 2) * 30 + w] = a2;
        S[(q * 4 + 3) * 30 + w] = a3;
    }
    __syncthreads();

    // phase 2a: stage M_all + row-softmax of S
    for (int v = tid; v < 960; v += 256)
        *(float4*)&U[v * 4] = *(const float4*)&ws[OFF_MALL + (size_t)b * 3840 + (size_t)v * 4];
    if (tid < 32) {
        float m = -1e30f;
        for (int w = 0; w < 30; w++) m = fmaxf(m, S[tid * 30 + w]);
        float s = 0.f;
        for (int w = 0; w < 30; w++) { float e = expf(S[tid * 30 + w] - m); S[tid * 30 + w] = e; s += e; }
        float inv = 1.f / s;
        for (int w = 0; w < 30; w++) S[tid * 30 + w] *= inv;
    }
    __syncthreads();

    // phase 2b: per (row, combo): v[16] = P1[row]·M[:, c*16..], softmax16, store
    {
        int c = tid >> 5, tl = tid & 31;
        float v[16];
        #pragma unroll
        for (int w = 0; w < 16; w++) v[w] = 0.f;
        for (int wp = 0; wp < 30; wp++) {
            float p1 = S[tl * 30 + wp];
            const float* Mr = &U[wp * 128 + c * 16];
            #pragma unroll
            for (int w = 0; w < 16; w++) v[w] += p1 * Mr[w];
        }
        float mx = v[0];
        #pragma unroll
        for (int w = 1; w < 16; w++) mx = fmaxf(mx, v[w]);
        float sum = 0.f;
        #pragma unroll
        for (int w = 0; w < 16; w++) { v[w] = expf(v[w] - mx); sum += v[w]; }
        float inv = ((t0 + tl) < 2000) ? (1.f / sum) : 0.f;
        #pragma unroll
        for (int w = 0; w < 16; w += 4) {
            float4 o = make_float4(v[w] * inv, v[w+1] * inv, v[w+2] * inv, v[w+3] * inv);
            *(float4*)&U[4224 + tl * 132 + c * 16 + w] = o;
        }
    }
    __syncthreads();

    // phase 2c: column sums over 32 rows -> PART
    if (tid < 128) {
        int combo = tid >> 4, w = tid & 15;
        float s = 0.f;
        for (int r = 0; r < 32; r++) s += U[4224 + r * 132 + tid];
        ws[OFF_PART + (((size_t)combo * 16 + b) * 63 + tile) * 16 + w] = s;
    }
}

// ---------------- final: reduce PART, (2D)->75->1 ----------------
__global__ __launch_bounds__(256) void k_final(float* ws, const float* as1W, const float* as1b,
                                               const float* as2W, const float* as2b, float* out){
    int blk = blockIdx.x; int o = blk >> 4, b = blk & 15;
    __shared__ float vec[600]; __shared__ float cm[32]; __shared__ float hb[80];
    int tid = threadIdx.x;
    if (tid < 32) {
        int half = tid / 16, wk = tid % 16;
        int combo = half ? (4 + o) : o;
        float s = 0.f;
        size_t base = OFF_PART + (((size_t)combo * 16 + b) * 63) * 16 + wk;
        for (int t = 0; t < 63; t++) s += ws[base + (size_t)t * 16];
        cm[tid] = s * (1.f / 2000.f);
    }
    __syncthreads();
    const float* oe = ws + OFF_OPTE + ((size_t)o * 256 + (size_t)b * 16) * 300;
    for (int idx = tid; idx < 600; idx += 256) {
        int half = idx / 300, e = idx % 300;
        float acc = 0.f;
        for (int w = 0; w < 16; w++) acc += cm[half * 16 + w] * oe[(size_t)w * 300 + e];
        vec[idx] = acc;
    }
    __syncthreads();
    if (tid < 75) {
        float acc = as1b[tid];
        for (int m = 0; m < 600; m++) acc += vec[m] * as1W[(size_t)tid * 600 + m];
        hb[tid] = fmaxf(acc, 0.f);
    }
    __syncthreads();
    if (tid == 0) {
        float s = as2b[0];
        for (int j = 0; j < 75; j++) s += hb[j] * as2W[j];
        out[b * 4 + o] = s;
    }
}

extern "C" void kernel_launch(void* const* d_in, const int* in_sizes, int n_in,
                              void* d_out, int out_size, void* d_ws, size_t ws_size,
                              hipStream_t stream) {
    float* ws = (float*)d_ws;
    const int* o1 = (const int*)d_in[0];
    const int* o2 = (const int*)d_in[1];
    const int* o3 = (const int*)d_in[2];
    const int* o4 = (const int*)d_in[3];
    const int* qin = (const int*)d_in[4];
    const int* ain = (const int*)d_in[5];
    const float* emb  = (const float*)d_in[6];
    const float* ceW  = (const float*)d_in[7];
    const float* ceb  = (const float*)d_in[8];
    const float* m1W  = (const float*)d_in[9];
    const float* m1b  = (const float*)d_in[10];
    const float* m2W  = (const float*)d_in[11];
    const float* m2b  = (const float*)d_in[12];
    const float* Wz   = (const float*)d_in[13];
    const float* bz   = (const float*)d_in[14];
    const float* Wo   = (const float*)d_in[15];
    const float* bo   = (const float*)d_in[16];
    const float* f1W  = (const float*)d_in[17];
    const float* f1b  = (const float*)d_in[18];
    const float* f2W  = (const float*)d_in[19];
    const float* f2b  = (const float*)d_in[20];
    const float* f3W  = (const float*)d_in[21];
    const float* f3b  = (const float*)d_in[22];
    const float* as1W = (const float*)d_in[23];
    const float* as1b = (const float*)d_in[24];
    const float* as2W = (const float*)d_in[25];
    const float* as2b = (const float*)d_in[26];

    k_pack<<<3800, 256, 0, stream>>>(ws, ceW, Wz, Wo, f1W, f2W, f3W);
    k_gather2<<<513, 320, 0, stream>>>(ws, emb, ain, qin, o1, o2, o3, o4);
    k_ce_coarse<<<890, 256, 0, stream>>>(ws, ceb);
    k_fused<<<1000, 256, 0, stream>>>(ws, emb, ain, ceb, m1W, m1b, m2W, m2b, bz, bo);
    k_scan1<<<2344, 256, 0, stream>>>(ws);
    k_scan2<<<19, 256, 0, stream>>>(ws);
    k_keysm<<<79, 256, 0, stream>>>(ws, f1b, f2b, f3b);
    k_matt<<<16, 256, 0, stream>>>(ws);
    k_attn<<<dim3(63, 16), 256, 0, stream>>>(ws);
    k_final<<<64, 256, 0, stream>>>(ws, as1W, as1b, as2W, as2b, (float*)d_out);
}

// Round 10
// 538.069 us; speedup vs baseline: 1.0925x; 1.0925x over previous
//
#include <hip/hip_runtime.h>
#include <math.h>

typedef unsigned short ushortT;
typedef short bf8 __attribute__((ext_vector_type(8)));
typedef float f32x4 __attribute__((ext_vector_type(4)));
typedef unsigned short us4 __attribute__((ext_vector_type(4)));

__device__ __forceinline__ float bf2f(ushortT u){
    union { unsigned int i; float f; } v; v.i = ((unsigned int)u) << 16; return v.f;
}
__device__ __forceinline__ ushortT f2bf(float f){
    union { float f; unsigned int i; } v; v.f = f;
    unsigned int x = v.i;
    return (ushortT)((x + 0x7fffu + ((x >> 16) & 1u)) >> 16);
}
__device__ __forceinline__ float4 f4add(float4 a, float4 b){
    return make_float4(a.x + b.x, a.y + b.y, a.z + b.z, a.w + b.w);
}

// B=16, T=2000, D=300; fp32 I/O. DIM x DIM matvecs: bf16-split MFMA
// (xh*wh + xh*wl + xl*wh), M=32 tiles, A split into LDS fragments.
// Round-8 structure; k_fused / k_ce_coarse at 512 threads for occupancy.

// ---------------- workspace layout (float indices), ~161.2 MB ----------------
constexpr size_t OFF_ART   = 0;           // 9,600,000  article emb -> o (in place)
constexpr size_t OFF_R2    = 9600000;     // 9,600,000  S5 -> z -> cs -> enc
constexpr size_t OFF_GATE  = 19200000;    // 9,600,000  S2 -> gate
constexpr size_t OFF_HC    = 28800000;    // 8,544,000  coarse CE outputs
constexpr size_t OFF_WB    = 37344000;    //   972,800 f32 = 10 matrices bf16 hi/lo frags
constexpr size_t OFF_QEMB  = 38316800;    //   144,000
constexpr size_t OFF_KEYSQ = 38460800;    //   144,000
constexpr size_t OFF_OPTE  = 38604800;    //   307,200
constexpr size_t OFF_KEYS2 = 38912000;    //   307,200
constexpr size_t OFF_KEYS3 = 39219200;    //   307,200
constexpr size_t OFF_SCANA = 39526400;    //   192,000  (40 chunks x 4800)
constexpr size_t OFF_SCANB = 39718400;    //   192,000
constexpr size_t OFF_CST   = 39910400;    //   192,000
constexpr size_t OFF_PART  = 40102400;    //   129,024
constexpr size_t OFF_MALL  = 40231424;    //    61,440  M_all = Q·K_all^T
// end = 40,292,864 floats = 161.2 MB

// HC rows: r2 [0,16000)=b*1000+g | r4 [16000,24000)=b*500+g
//          r10 [24000,27200)=b*200+g | r25 [27200,28480)=b*80+g
// S2 (at OFF_GATE): 16000 rows = b*1000+g | S5 (at OFF_R2): 6400 rows = b*400+g

// WB (ushort units): ((mp + kt)*19 + nt)*512 + lane*8 + j
//   mp = matrix*20 + part*10
//   matrix: 0..4 ce, 5 Wz, 6 Wo, 7 f1W, 8 f2W, 9 f3W; part: 0 hi, 1 lo

__global__ void k_pack(float* ws, const float* ceW, const float* Wz, const float* Wo,
                       const float* f1W, const float* f2W, const float* f3W){
    int id = blockIdx.x * 256 + threadIdx.x;
    if (id >= 972800) return;          // 10 * 97280
    int m = id / 97280; int rr = id % 97280;
    int kt = rr / 9728; rr %= 9728;
    int nt = rr / 512;  rr %= 512;
    int lane = rr / 8; int j = rr % 8;
    int d = kt * 32 + (lane >> 4) * 8 + j;
    int e = nt * 16 + (lane & 15);
    float w = 0.f;
    if (d < 300 && e < 300) {
        const float* src = (m < 5) ? (ceW + (size_t)m * 90000)
                         : (m == 5) ? Wz : (m == 6) ? Wo
                         : (m == 7) ? f1W : (m == 8) ? f2W : f3W;
        w = src[(size_t)e * 300 + d];
    }
    ushortT hi = f2bf(w);
    ushortT lo = f2bf(w - bf2f(hi));
    ushortT* wb = (ushortT*)(ws + OFF_WB);
    wb[((size_t)(m * 20 + kt) * 19 + nt) * 512 + lane * 8 + j] = hi;
    wb[((size_t)(m * 20 + 10 + kt) * 19 + nt) * 512 + lane * 8 + j] = lo;
}

__device__ __forceinline__ bf8 load_bfrag(const ushortT* wb, int mp, int kt, int nt, int lane){
    return *(const bf8*)(wb + (((size_t)(mp + kt) * 19 + nt) * 512 + lane * 8));
}
__device__ __forceinline__ bf8 lds_afrag(const ushortT* LA, int tile, int kt, int part, int lane){
    return *(const bf8*)(LA + ((tile * 10 + kt) * 2 + part) * 512 + lane * 8);
}
__device__ __forceinline__ void lds_store_split(ushortT* LA, int r, int dc4, float4 s){
    int kt = dc4 / 8;
    int kk = (dc4 % 8) * 4;
    int quad = kk / 8, j = kk % 8;
    int lane = quad * 16 + (r & 15), tile = r >> 4;
    us4 h, l;
    h.x = f2bf(s.x); l.x = f2bf(s.x - bf2f(h.x));
    h.y = f2bf(s.y); l.y = f2bf(s.y - bf2f(h.y));
    h.z = f2bf(s.z); l.z = f2bf(s.z - bf2f(h.z));
    h.w = f2bf(s.w); l.w = f2bf(s.w - bf2f(h.w));
    int base = ((tile * 10 + kt) * 2) * 512 + lane * 8 + j;
    *(us4*)&LA[base] = h;
    *(us4*)&LA[base + 512] = l;
}
__device__ __forceinline__ void lds_zero_kt9(ushortT* LA, int tid, int step){
    for (int i = tid; i < 1024; i += step) {
        int sl = i >> 8, u = i & 255;
        int slice = (sl < 2) ? (18 + sl) : (36 + sl); // 18,19,38,39
        *(unsigned int*)&LA[slice * 512 + u * 2] = 0u;
    }
}

// ---------------- gather + inline S2/S5 group sums ----------------
// blocks [0,160): article, gb = b*10+c covers t in [c*200, c*200+200)
// blocks [160,513): question + options (flat f4 ids)
__global__ __launch_bounds__(320) void k_gather2(float* ws, const float* emb,
                         const int* art_in, const int* q_in,
                         const int* o1, const int* o2, const int* o3, const int* o4){
    int gb = blockIdx.x, tid = threadIdx.x;
    const float4* embv = (const float4*)emb;
    if (gb < 160) {
        if (tid >= 300) return;
        int b = gb / 10, c = gb % 10;
        int rg = tid / 75, d4 = tid % 75;
        int tbase = c * 200 + rg * 50;
        float4 s2 = make_float4(0.f,0.f,0.f,0.f), s5 = s2;
        float4* artv  = (float4*)(ws + OFF_ART);
        float4* s2v   = (float4*)(ws + OFF_GATE);
        float4* s5v   = (float4*)(ws + OFF_R2);
        for (int i = 0; i < 50; i++) {
            int t = tbase + i;
            int tok = art_in[b * 2000 + t];
            float4 v = embv[(size_t)tok * 75 + d4];
            artv[((size_t)b * 2000 + t) * 75 + d4] = v;
            s2 = f4add(s2, v); s5 = f4add(s5, v);
            if ((i & 1) == 1) { s2v[((size_t)b * 1000 + (t >> 1)) * 75 + d4] = s2; s2 = make_float4(0.f,0.f,0.f,0.f); }
            if (i % 5 == 4)   { s5v[((size_t)b * 400 + t / 5) * 75 + d4] = s5;   s5 = make_float4(0.f,0.f,0.f,0.f); }
        }
    } else {
        int id = (gb - 160) * 320 + tid;
        if (id < 36000) {
            size_t row = id / 75; int wi = id % 75;
            ((float4*)(ws + OFF_QEMB))[id] = embv[(size_t)q_in[row] * 75 + wi];
        } else if (id < 112800) {
            int i3 = id - 36000; size_t row = i3 / 75; int wi = i3 % 75;
            int opt = (int)(row / 256); int rr = (int)(row % 256);
            const int* op = (opt == 0) ? o1 : (opt == 1) ? o2 : (opt == 2) ? o3 : o4;
            ((float4*)(ws + OFF_OPTE))[i3] = embv[(size_t)op[rr] * 75 + wi];
        }
    }
}

// ---------------- coarse CE (r=2,4,10,25): M=32, LDS-split A, MFMA, 512 thr ----------------
// blocks: [0,40) r25 | [40,140) r10 | [140,390) r4 | [390,890) r2
__global__ __launch_bounds__(512) void k_ce_coarse(float* ws, const float* ceb){
    int gb = blockIdx.x;
    int kind, rows0, wi, rowLocal0;
    if (gb < 40)       { kind = 3; rows0 = 27200; wi = 4; rowLocal0 = gb * 32; }
    else if (gb < 140) { kind = 2; rows0 = 24000; wi = 3; rowLocal0 = (gb - 40) * 32; }
    else if (gb < 390) { kind = 1; rows0 = 16000; wi = 2; rowLocal0 = (gb - 140) * 32; }
    else               { kind = 0; rows0 = 0;     wi = 1; rowLocal0 = (gb - 390) * 32; }

    __shared__ ushortT LA[20480];
    int tid = threadIdx.x;
    lds_zero_kt9(LA, tid, 512);
    __syncthreads();
    const float4* S2v = (const float4*)(ws + OFF_GATE);
    const float4* S5v = (const float4*)(ws + OFF_R2);
    for (int v = tid; v < 2400; v += 512) {
        int r = v / 75, dc4 = v % 75;
        int R = rowLocal0 + r;
        float4 s;
        if (kind == 0) {
            s = S2v[(size_t)R * 75 + dc4];
        } else if (kind == 1) {
            int b = R / 500, g = R % 500;
            const float4* p = S2v + ((size_t)b * 1000 + 2 * g) * 75 + dc4;
            s = f4add(p[0], p[75]);
        } else if (kind == 2) {
            int b = R / 200, g = R % 200;
            const float4* p = S5v + ((size_t)b * 400 + 2 * g) * 75 + dc4;
            s = f4add(p[0], p[75]);
        } else {
            int b = R / 80, g = R % 80;
            const float4* p = S5v + ((size_t)b * 400 + 5 * g) * 75 + dc4;
            s = f4add(f4add(p[0], p[75]), f4add(p[150], p[225]));
            s = f4add(s, p[300]);
        }
        lds_store_split(LA, r, dc4, s);
    }
    __syncthreads();

    int lane = tid & 63, wv = tid >> 6;          // 8 waves
    int mrow = lane & 15, quad = lane >> 4;
    const ushortT* wb = (const ushortT*)(ws + OFF_WB);
    int mpH = wi * 20, mpL = wi * 20 + 10;

    for (int p = 0; p < 3; p++) {
        int nt = wv + p * 8; if (nt >= 19) break;
        f32x4 a0 = {0.f,0.f,0.f,0.f}, a1 = {0.f,0.f,0.f,0.f};
        #pragma unroll
        for (int kt = 0; kt < 10; kt++) {
            bf8 Ah0 = lds_afrag(LA, 0, kt, 0, lane), Al0 = lds_afrag(LA, 0, kt, 1, lane);
            bf8 Ah1 = lds_afrag(LA, 1, kt, 0, lane), Al1 = lds_afrag(LA, 1, kt, 1, lane);
            bf8 Bh = load_bfrag(wb, mpH, kt, nt, lane);
            bf8 Bl = load_bfrag(wb, mpL, kt, nt, lane);
            a0 = __builtin_amdgcn_mfma_f32_16x16x32_bf16(Ah0, Bh, a0, 0, 0, 0);
            a1 = __builtin_amdgcn_mfma_f32_16x16x32_bf16(Ah1, Bh, a1, 0, 0, 0);
            a0 = __builtin_amdgcn_mfma_f32_16x16x32_bf16(Ah0, Bl, a0, 0, 0, 0);
            a1 = __builtin_amdgcn_mfma_f32_16x16x32_bf16(Ah1, Bl, a1, 0, 0, 0);
            a0 = __builtin_amdgcn_mfma_f32_16x16x32_bf16(Al0, Bh, a0, 0, 0, 0);
            a1 = __builtin_amdgcn_mfma_f32_16x16x32_bf16(Al1, Bh, a1, 0, 0, 0);
        }
        int e = nt * 16 + mrow;
        if (e < 300) {
            float bv = ceb[wi * 300 + e];
            #pragma unroll
            for (int q = 0; q < 4; q++) {
                int r0 = rows0 + rowLocal0 + quad * 4 + q;
                ws[OFF_HC + (size_t)r0 * 300 + e] = fmaxf(a0[q] + bv, 0.f);
                ws[OFF_HC + (size_t)(r0 + 16) * 300 + e] = fmaxf(a1[q] + bv, 0.f);
            }
        }
    }
}

// ---------------- fused: ce0 + Wz + Wo MFMA (shared A) + gate/z/o epilogue, 512 thr ----------------
// gate -> GATE, z -> R2, o -> ART (in place; ART dead afterwards)
__global__ __launch_bounds__(512) void k_fused(float* ws, const float* ceb,
                                               const float* m1W, const float* m1b,
                                               const float* m2W, const float* m2b,
                                               const float* bz, const float* bo){
    int row0 = blockIdx.x * 32;
    __shared__ ushortT LA[20480];
    int tid = threadIdx.x;
    lds_zero_kt9(LA, tid, 512);
    __syncthreads();
    for (int v = tid; v < 2400; v += 512) {
        int r = v / 75, dc4 = v % 75;
        float4 s = *(const float4*)&ws[OFF_ART + (size_t)(row0 + r) * 300 + dc4 * 4];
        lds_store_split(LA, r, dc4, s);
    }
    __syncthreads();

    float w1[3][5], b1[3], w2[3], b2;
    #pragma unroll
    for (int k = 0; k < 3; k++) {
        #pragma unroll
        for (int i = 0; i < 5; i++) w1[k][i] = m1W[k * 5 + i];
        b1[k] = m1b[k]; w2[k] = m2W[k];
    }
    b2 = m2b[0];

    int lane = tid & 63, wv = tid >> 6;          // 8 waves
    int mrow = lane & 15, quad = lane >> 4;
    const ushortT* wb = (const ushortT*)(ws + OFF_WB);

    for (int p = 0; p < 3; p++) {
        int nt = wv + p * 8; if (nt >= 19) break;
        f32x4 aA0 = {0.f,0.f,0.f,0.f}, aA1 = aA0;
        f32x4 aZ0 = aA0, aZ1 = aA0, aO0 = aA0, aO1 = aA0;
        #pragma unroll
        for (int kt = 0; kt < 10; kt++) {
            bf8 Ah0 = lds_afrag(LA, 0, kt, 0, lane), Al0 = lds_afrag(LA, 0, kt, 1, lane);
            bf8 Ah1 = lds_afrag(LA, 1, kt, 0, lane), Al1 = lds_afrag(LA, 1, kt, 1, lane);
            bf8 BAh = load_bfrag(wb, 0,   kt, nt, lane);
            bf8 BAl = load_bfrag(wb, 10,  kt, nt, lane);
            bf8 BZh = load_bfrag(wb, 100, kt, nt, lane);
            bf8 BZl = load_bfrag(wb, 110, kt, nt, lane);
            bf8 BOh = load_bfrag(wb, 120, kt, nt, lane);
            bf8 BOl = load_bfrag(wb, 130, kt, nt, lane);
            aA0 = __builtin_amdgcn_mfma_f32_16x16x32_bf16(Ah0, BAh, aA0, 0, 0, 0);
            aZ0 = __builtin_amdgcn_mfma_f32_16x16x32_bf16(Ah0, BZh, aZ0, 0, 0, 0);
            aO0 = __builtin_amdgcn_mfma_f32_16x16x32_bf16(Ah0, BOh, aO0, 0, 0, 0);
            aA1 = __builtin_amdgcn_mfma_f32_16x16x32_bf16(Ah1, BAh, aA1, 0, 0, 0);
            aZ1 = __builtin_amdgcn_mfma_f32_16x16x32_bf16(Ah1, BZh, aZ1, 0, 0, 0);
            aO1 = __builtin_amdgcn_mfma_f32_16x16x32_bf16(Ah1, BOh, aO1, 0, 0, 0);
            aA0 = __builtin_amdgcn_mfma_f32_16x16x32_bf16(Ah0, BAl, aA0, 0, 0, 0);
            aZ0 = __builtin_amdgcn_mfma_f32_16x16x32_bf16(Ah0, BZl, aZ0, 0, 0, 0);
            aO0 = __builtin_amdgcn_mfma_f32_16x16x32_bf16(Ah0, BOl, aO0, 0, 0, 0);
            aA1 = __builtin_amdgcn_mfma_f32_16x16x32_bf16(Ah1, BAl, aA1, 0, 0, 0);
            aZ1 = __builtin_amdgcn_mfma_f32_16x16x32_bf16(Ah1, BZl, aZ1, 0, 0, 0);
            aO1 = __builtin_amdgcn_mfma_f32_16x16x32_bf16(Ah1, BOl, aO1, 0, 0, 0);
            aA0 = __builtin_amdgcn_mfma_f32_16x16x32_bf16(Al0, BAh, aA0, 0, 0, 0);
            aZ0 = __builtin_amdgcn_mfma_f32_16x16x32_bf16(Al0, BZh, aZ0, 0, 0, 0);
            aO0 = __builtin_amdgcn_mfma_f32_16x16x32_bf16(Al0, BOh, aO0, 0, 0, 0);
            aA1 = __builtin_amdgcn_mfma_f32_16x16x32_bf16(Al1, BAh, aA1, 0, 0, 0);
            aZ1 = __builtin_amdgcn_mfma_f32_16x16x32_bf16(Al1, BZh, aZ1, 0, 0, 0);
            aO1 = __builtin_amdgcn_mfma_f32_16x16x32_bf16(Al1, BOh, aO1, 0, 0, 0);
        }
        int e = nt * 16 + mrow;
        if (e < 300) {
            float cebe = ceb[e], bze = bz[e], boe = bo[e];
            #pragma unroll
            for (int tile = 0; tile < 2; tile++) {
                #pragma unroll
                for (int q = 0; q < 4; q++) {
                    float vA = tile ? aA1[q] : aA0[q];
                    float vZ = tile ? aZ1[q] : aZ0[q];
                    float vO = tile ? aO1[q] : aO0[q];
                    int row = row0 + tile * 16 + quad * 4 + q;
                    int bb = row / 2000, t = row % 2000;
                    size_t c1 = OFF_HC + ((size_t)bb * 1000 + t / 2) * 300;
                    size_t c2 = OFF_HC + (16000 + (size_t)bb * 500 + t / 4) * 300;
                    size_t c3 = OFF_HC + (24000 + (size_t)bb * 200 + t / 10) * 300;
                    size_t c4 = OFF_HC + (27200 + (size_t)bb * 80 + t / 25) * 300;
                    float y0 = fmaxf(vA + cebe, 0.f);
                    float y1 = ws[c1 + e] * 0.5f;
                    float y2 = ws[c2 + e] * 0.25f;
                    float y3 = ws[c3 + e] * 0.1f;
                    float y4 = ws[c4 + e] * 0.04f;
                    float gacc = b2;
                    #pragma unroll
                    for (int k = 0; k < 3; k++) {
                        float a = b1[k] + y0 * w1[k][0] + y1 * w1[k][1] + y2 * w1[k][2]
                                + y3 * w1[k][3] + y4 * w1[k][4];
                        gacc += fmaxf(a, 0.f) * w2[k];
                    }
                    ws[OFF_GATE + (size_t)row * 300 + e] = fmaxf(gacc, 0.f);
                    ws[OFF_R2 + (size_t)row * 300 + e] = tanhf(vZ + bze);
                    ws[OFF_ART + (size_t)row * 300 + e] = tanhf(vO + boe);
                }
            }
        }
    }
}

// ---------------- MRU scan: 40 chunks x 50 steps ----------------
__global__ void k_scan1(float* ws){
    int tid = blockIdx.x * 256 + threadIdx.x;
    if (tid >= 192000) return;
    int c = tid / 4800, ch = tid % 4800;
    int b = ch / 300, d = ch % 300;
    size_t base = (size_t)b * 2000 * 300 + d;
    float A = 1.f, Bv = 0.f;
    int t0 = c * 50;
    for (int k = 0; k < 50; k++) {
        size_t ix = base + (size_t)(t0 + k) * 300;
        float g = ws[OFF_GATE + ix], zz = ws[OFF_R2 + ix];
        Bv = g * Bv + (1.f - g) * zz;
        A *= g;
    }
    ws[OFF_SCANA + tid] = A;
    ws[OFF_SCANB + tid] = Bv;
}

__global__ void k_scan2(float* ws){
    int ch = blockIdx.x * 256 + threadIdx.x;
    if (ch >= 4800) return;
    float c = 0.f;
    for (int j = 0; j < 40; j++) {
        ws[OFF_CST + (size_t)j * 4800 + ch] = c;
        c = ws[OFF_SCANA + (size_t)j * 4800 + ch] * c + ws[OFF_SCANB + (size_t)j * 4800 + ch];
    }
}

// scan3: recompute cs and write enc = o * cs  (o from ART region)
__global__ void k_scan3(float* ws){
    int tid = blockIdx.x * 256 + threadIdx.x;
    if (tid >= 192000) return;
    int c = tid / 4800, ch = tid % 4800;
    int b = ch / 300, d = ch % 300;
    size_t base = (size_t)b * 2000 * 300 + d;
    float cc = ws[OFF_CST + tid];
    int t0 = c * 50;
    for (int k = 0; k < 50; k++) {
        size_t ix = base + (size_t)(t0 + k) * 300;
        float g = ws[OFF_GATE + ix], zz = ws[OFF_R2 + ix];
        cc = g * cc + (1.f - g) * zz;
        ws[OFF_R2 + ix] = ws[OFF_ART + ix] * cc;
    }
}

// ---------------- key projections via MFMA: f1(q), f2(opt), f3(opt) ----------------
__global__ __launch_bounds__(256) void k_keysm(float* ws, const float* f1b,
                                               const float* f2b, const float* f3b){
    int gb = blockIdx.x;
    int wm, rowLocal0; size_t inoff, outoff; const float* bias;
    if (gb < 15)      { wm = 7; inoff = OFF_QEMB; outoff = OFF_KEYSQ; bias = f1b; rowLocal0 = gb * 32; }
    else if (gb < 47) { wm = 8; inoff = OFF_OPTE; outoff = OFF_KEYS2; bias = f2b; rowLocal0 = (gb - 15) * 32; }
    else              { wm = 9; inoff = OFF_OPTE; outoff = OFF_KEYS3; bias = f3b; rowLocal0 = (gb - 47) * 32; }

    __shared__ ushortT LA[20480];
    int tid = threadIdx.x;
    lds_zero_kt9(LA, tid, 256);
    __syncthreads();
    for (int v = tid; v < 2400; v += 256) {
        int r = v / 75, dc4 = v % 75;
        float4 s = *(const float4*)&ws[inoff + (size_t)(rowLocal0 + r) * 300 + dc4 * 4];
        lds_store_split(LA, r, dc4, s);
    }
    __syncthreads();

    int lane = tid & 63, wv = tid >> 6;
    int mrow = lane & 15, quad = lane >> 4;
    const ushortT* wb = (const ushortT*)(ws + OFF_WB);
    int mpH = wm * 20, mpL = wm * 20 + 10;

    for (int p = 0; p < 5; p++) {
        int nt = wv + p * 4; if (nt >= 19) break;
        f32x4 a0 = {0.f,0.f,0.f,0.f}, a1 = {0.f,0.f,0.f,0.f};
        #pragma unroll
        for (int kt = 0; kt < 10; kt++) {
            bf8 Ah0 = lds_afrag(LA, 0, kt, 0, lane), Al0 = lds_afrag(LA, 0, kt, 1, lane);
            bf8 Ah1 = lds_afrag(LA, 1, kt, 0, lane), Al1 = lds_afrag(LA, 1, kt, 1, lane);
            bf8 Bh = load_bfrag(wb, mpH, kt, nt, lane);
            bf8 Bl = load_bfrag(wb, mpL, kt, nt, lane);
            a0 = __builtin_amdgcn_mfma_f32_16x16x32_bf16(Ah0, Bh, a0, 0, 0, 0);
            a1 = __builtin_amdgcn_mfma_f32_16x16x32_bf16(Ah1, Bh, a1, 0, 0, 0);
            a0 = __builtin_amdgcn_mfma_f32_16x16x32_bf16(Ah0, Bl, a0, 0, 0, 0);
            a1 = __builtin_amdgcn_mfma_f32_16x16x32_bf16(Ah1, Bl, a1, 0, 0, 0);
            a0 = __builtin_amdgcn_mfma_f32_16x16x32_bf16(Al0, Bh, a0, 0, 0, 0);
            a1 = __builtin_amdgcn_mfma_f32_16x16x32_bf16(Al1, Bh, a1, 0, 0, 0);
        }
        int e = nt * 16 + mrow;
        if (e < 300) {
            float bv = bias[e];
            #pragma unroll
            for (int q = 0; q < 4; q++) {
                int r0 = rowLocal0 + quad * 4 + q;
                ws[outoff + (size_t)r0 * 300 + e] = a0[q] + bv;
                ws[outoff + (size_t)(r0 + 16) * 300 + e] = a1[q] + bv;
            }
        }
    }
}

// ---------------- M_all = Q · K_all^T per batch (30 x 128, K=300) ----------------
__global__ __launch_bounds__(256) void k_matt(float* ws){
    int b = blockIdx.x;
    __shared__ float Q[30 * 300];
    int tid = threadIdx.x;
    for (int v = tid; v < 2250; v += 256)
        *(float4*)&Q[v * 4] = *(const float4*)&ws[OFF_QEMB + (size_t)b * 9000 + (size_t)v * 4];
    __syncthreads();
    int cw = tid & 127, half = tid >> 7;
    int combo = cw >> 4, w = cw & 15;
    size_t kbase = (combo < 4)
        ? OFF_KEYS2 + ((size_t)combo * 256 + (size_t)b * 16 + w) * 300
        : OFF_KEYS3 + ((size_t)(combo - 4) * 256 + (size_t)b * 16 + w) * 300;
    const float4* kr = (const float4*)&ws[kbase];
    for (int wp = half * 15; wp < half * 15 + 15; wp++) {
        const float4* qr = (const float4*)&Q[wp * 300];
        float a = 0.f;
        #pragma unroll 5
        for (int j = 0; j < 75; j++) {
            float4 k = kr[j], q = qr[j];
            a += k.x * q.x + k.y * q.y + k.z * q.z + k.w * q.w;
        }
        ws[OFF_MALL + (size_t)b * 3840 + (size_t)wp * 128 + cw] = a;
    }
}

// ---------------- attention: S1+softmax, S_all = P1·M_all + softmax + colsums ----------------
__global__ __launch_bounds__(256) void k_attn(float* ws){
    int tile = blockIdx.x, b = blockIdx.y;
    int t0 = tile * 32;
    __shared__ __align__(16) float U[9728];
    __shared__ float S[32 * 30];
    int tid = threadIdx.x;

    for (int v = tid; v < 2432; v += 256) {
        int r = v / 76, c = v % 76;
        int t = t0 + r;
        float4 val = make_float4(0.f, 0.f, 0.f, 0.f);
        if (c < 75 && t < 2000)
            val = *(const float4*)&ws[OFF_R2 + ((size_t)b * 2000 + t) * 300 + (size_t)c * 4];
        *(float4*)&U[r * 304 + c * 4] = val;
    }
    __syncthreads();

    if (tid < 240) {
        int q = tid / 30, w = tid % 30;
        const float4* kr = (const float4*)&ws[OFF_KEYSQ + (size_t)b * 9000 + (size_t)w * 300];
        const float4* x0 = (const float4*)&U[(q * 4 + 0) * 304];
        const float4* x1 = (const float4*)&U[(q * 4 + 1) * 304];
        const float4* x2 = (const float4*)&U[(q * 4 + 2) * 304];
        const float4* x3 = (const float4*)&U[(q * 4 + 3) * 304];
        float a0 = 0.f, a1 = 0.f, a2 = 0.f, a3 = 0.f;
        #pragma unroll 5
        for (int j = 0; j < 75; j++) {
            float4 k = kr[j];
            float4 v0 = x0[j], v1 = x1[j], v2 = x2[j], v3 = x3[j];
            a0 += v0.x * k.x + v0.y * k.y + v0.z * k.z + v0.w * k.w;
            a1 += v1.x * k.x + v1.y * k.y + v1.z * k.z + v1.w * k.w;
            a2 += v2.x * k.x + v2.y * k.y + v2.z * k.z + v2.w * k.w;
            a3 += v3.x * k.x + v3.y * k.y + v3.z * k.z + v3.w * k.w;
        }
        S[(q * 4 + 0) * 30 + w] = a0;
        S[(q * 4 + 1) * 30 + w] = a1;
        S[(q * 4 + 2) * 30 + w] = a2;
        S[(q * 4 + 3) * 30 + w] = a3;
    }
    __syncthreads();

    for (int v = tid; v < 960; v += 256)
        *(float4*)&U[v * 4] = *(const float4*)&ws[OFF_MALL + (size_t)b * 3840 + (size_t)v * 4];
    if (tid < 32) {
        float m = -1e30f;
        for (int w = 0; w < 30; w++) m = fmaxf(m, S[tid * 30 + w]);
        float s = 0.f;
        for (int w = 0; w < 30; w++) { float e = expf(S[tid * 30 + w] - m); S[tid * 30 + w] = e; s += e; }
        float inv = 1.f / s;
        for (int w = 0; w < 30; w++) S[tid * 30 + w] *= inv;
    }
    __syncthreads();

    {
        int c = tid >> 5, tl = tid & 31;
        float v[16];
        #pragma unroll
        for (int w = 0; w < 16; w++) v[w] = 0.f;
        for (int wp = 0; wp < 30; wp++) {
            float p1 = S[tl * 30 + wp];
            const float* Mr = &U[wp * 128 + c * 16];
            #pragma unroll
            for (int w = 0; w < 16; w++) v[w] += p1 * Mr[w];
        }
        float mx = v[0];
        #pragma unroll
        for (int w = 1; w < 16; w++) mx = fmaxf(mx, v[w]);
        float sum = 0.f;
        #pragma unroll
        for (int w = 0; w < 16; w++) { v[w] = expf(v[w] - mx); sum += v[w]; }
        float inv = ((t0 + tl) < 2000) ? (1.f / sum) : 0.f;
        #pragma unroll
        for (int w = 0; w < 16; w += 4) {
            float4 o = make_float4(v[w] * inv, v[w+1] * inv, v[w+2] * inv, v[w+3] * inv);
            *(float4*)&U[4224 + tl * 132 + c * 16 + w] = o;
        }
    }
    __syncthreads();

    if (tid < 128) {
        int combo = tid >> 4, w = tid & 15;
        float s = 0.f;
        for (int r = 0; r < 32; r++) s += U[4224 + r * 132 + tid];
        ws[OFF_PART + (((size_t)combo * 16 + b) * 63 + tile) * 16 + w] = s;
    }
}

// ---------------- final: reduce PART, (2D)->75->1 ----------------
__global__ __launch_bounds__(256) void k_final(float* ws, const float* as1W, const float* as1b,
                                               const float* as2W, const float* as2b, float* out){
    int blk = blockIdx.x; int o = blk >> 4, b = blk & 15;
    __shared__ float vec[600]; __shared__ float cm[32]; __shared__ float hb[80];
    int tid = threadIdx.x;
    if (tid < 32) {
        int half = tid / 16, wk = tid % 16;
        int combo = half ? (4 + o) : o;
        float s = 0.f;
        size_t base = OFF_PART + (((size_t)combo * 16 + b) * 63) * 16 + wk;
        for (int t = 0; t < 63; t++) s += ws[base + (size_t)t * 16];
        cm[tid] = s * (1.f / 2000.f);
    }
    __syncthreads();
    const float* oe = ws + OFF_OPTE + ((size_t)o * 256 + (size_t)b * 16) * 300;
    for (int idx = tid; idx < 600; idx += 256) {
        int half = idx / 300, e = idx % 300;
        float acc = 0.f;
        for (int w = 0; w < 16; w++) acc += cm[half * 16 + w] * oe[(size_t)w * 300 + e];
        vec[idx] = acc;
    }
    __syncthreads();
    if (tid < 75) {
        float acc = as1b[tid];
        for (int m = 0; m < 600; m++) acc += vec[m] * as1W[(size_t)tid * 600 + m];
        hb[tid] = fmaxf(acc, 0.f);
    }
    __syncthreads();
    if (tid == 0) {
        float s = as2b[0];
        for (int j = 0; j < 75; j++) s += hb[j] * as2W[j];
        out[b * 4 + o] = s;
    }
}

extern "C" void kernel_launch(void* const* d_in, const int* in_sizes, int n_in,
                              void* d_out, int out_size, void* d_ws, size_t ws_size,
                              hipStream_t stream) {
    float* ws = (float*)d_ws;
    const int* o1 = (const int*)d_in[0];
    const int* o2 = (const int*)d_in[1];
    const int* o3 = (const int*)d_in[2];
    const int* o4 = (const int*)d_in[3];
    const int* qin = (const int*)d_in[4];
    const int* ain = (const int*)d_in[5];
    const float* emb  = (const float*)d_in[6];
    const float* ceW  = (const float*)d_in[7];
    const float* ceb  = (const float*)d_in[8];
    const float* m1W  = (const float*)d_in[9];
    const float* m1b  = (const float*)d_in[10];
    const float* m2W  = (const float*)d_in[11];
    const float* m2b  = (const float*)d_in[12];
    const float* Wz   = (const float*)d_in[13];
    const float* bz   = (const float*)d_in[14];
    const float* Wo   = (const float*)d_in[15];
    const float* bo   = (const float*)d_in[16];
    const float* f1W  = (const float*)d_in[17];
    const float* f1b  = (const float*)d_in[18];
    const float* f2W  = (const float*)d_in[19];
    const float* f2b  = (const float*)d_in[20];
    const float* f3W  = (const float*)d_in[21];
    const float* f3b  = (const float*)d_in[22];
    const float* as1W = (const float*)d_in[23];
    const float* as1b = (const float*)d_in[24];
    const float* as2W = (const float*)d_in[25];
    const float* as2b = (const float*)d_in[26];

    k_pack<<<3800, 256, 0, stream>>>(ws, ceW, Wz, Wo, f1W, f2W, f3W);
    k_gather2<<<513, 320, 0, stream>>>(ws, emb, ain, qin, o1, o2, o3, o4);
    k_ce_coarse<<<890, 512, 0, stream>>>(ws, ceb);
    k_fused<<<1000, 512, 0, stream>>>(ws, ceb, m1W, m1b, m2W, m2b, bz, bo);
    k_scan1<<<750, 256, 0, stream>>>(ws);
    k_scan2<<<19, 256, 0, stream>>>(ws);
    k_scan3<<<750, 256, 0, stream>>>(ws);
    k_keysm<<<79, 256, 0, stream>>>(ws, f1b, f2b, f3b);
    k_matt<<<16, 256, 0, stream>>>(ws);
    k_attn<<<dim3(63, 16), 256, 0, stream>>>(ws);
    k_final<<<64, 256, 0, stream>>>(ws, as1W, as1b, as2W, as2b, (float*)d_out);
}